// Round 4
// baseline (79.253 us; speedup 1.0000x reference)
//
#include <hip/hip_runtime.h>
#include <hip/hip_bf16.h>
#include <stdint.h>

#define BATCH 8192
#define NSAMP 10
#define FDIM 128
#define K2 256
#define EDIM 128
#define NLAB 16384
#define EPSF 1e-6f

#define CPAD 264     // 256 + 8 bf16 pad -> 528B row stride, 16B aligned, 2-way bank alias (free)
#define NPB 512      // partial rows per sel (one per stage1 block)
#define PARTIAL_BYTES (2 * NPB * 132 * 4)   // 540,672

typedef __bf16 bf16x8 __attribute__((ext_vector_type(8)));
typedef float f32x4 __attribute__((ext_vector_type(4)));

struct alignas(8) bfx4 { __hip_bfloat16 a, b, c, d; };

// ================= single fused kernel =================
// blocks 0..255   : gather 32 batch rows -> LDS, then 128x32 GEMM tile + relu
// blocks 256..1279: update_vector stage 1 (+ last finisher does stage 2 inline)
__global__ __launch_bounds__(256) void fusedA(
    const int* __restrict__ nodes, const int* __restrict__ neigh,
    const int* __restrict__ pos_idx, const int* __restrict__ neg_idx,
    const float* __restrict__ feats,
    const float* __restrict__ pos_vec, const float* __restrict__ neg_vec,
    const float* __restrict__ W,         // [128][256] fp32 row-major
    float* __restrict__ partial,
    unsigned* __restrict__ cnt,
    float* __restrict__ out)             // [128][8192] then pos[128], neg[128]
{
    __shared__ __hip_bfloat16 comb[32][CPAD];
    __shared__ float red[4][132];
    __shared__ int lastFlag;

    int blk  = blockIdx.x;
    int tid  = threadIdx.x;
    int lane = tid & 63;
    int wv   = tid >> 6;
    int hl   = lane & 31;        // lane within half-wave
    int half = lane >> 5;        // 0 or 1
    int hw   = wv * 2 + half;    // half-wave id 0..7

    if (blk < 256) {
        int n0 = blk * 32;       // this block's batch-row base

        // ---- phase 1: gather self + neighbor mean, 4 rows per half-wave ----
        #pragma unroll 2
        for (int rr = 0; rr < 4; ++rr) {
            int lr  = hw * 4 + rr;           // local row 0..31
            int row = n0 + lr;
            int ids[NSAMP + 1];
            ids[0] = nodes[row];
            #pragma unroll
            for (int j = 0; j < NSAMP; ++j) ids[1 + j] = neigh[row * NSAMP + j];

            f32x4 s = ((const f32x4*)(feats + (size_t)ids[0] * FDIM))[hl];
            f32x4 acc = {0.f, 0.f, 0.f, 0.f};
            #pragma unroll
            for (int j = 0; j < NSAMP; ++j) {
                f32x4 v = ((const f32x4*)(feats + (size_t)ids[1 + j] * FDIM))[hl];
                acc += v;
            }
            acc *= 0.1f;

            bfx4 t;
            t.a = __float2bfloat16(s[0]); t.b = __float2bfloat16(s[1]);
            t.c = __float2bfloat16(s[2]); t.d = __float2bfloat16(s[3]);
            *(bfx4*)(&comb[lr][4 * hl]) = t;
            t.a = __float2bfloat16(acc[0]); t.b = __float2bfloat16(acc[1]);
            t.c = __float2bfloat16(acc[2]); t.d = __float2bfloat16(acc[3]);
            *(bfx4*)(&comb[lr][FDIM + 4 * hl]) = t;
        }
        __syncthreads();

        // ---- phase 2: out[m0..m0+31][n0..n0+31] = relu(W @ comb^T) ----
        int llo = lane & 15, lhi = lane >> 4;
        int m0 = wv * 32;
        int n0b = blk * 32;

        f32x4 acc[2][2];
        #pragma unroll
        for (int i = 0; i < 2; ++i)
            #pragma unroll
            for (int j = 0; j < 2; ++j) { f32x4 z = {0.f,0.f,0.f,0.f}; acc[i][j] = z; }

        #pragma unroll
        for (int k0 = 0; k0 < K2; k0 += 32) {
            bf16x8 a[2], b[2];
            #pragma unroll
            for (int mi = 0; mi < 2; ++mi) {
                const float* wp = W + (size_t)(m0 + 16*mi + llo) * K2 + k0 + lhi*8;
                f32x4 w0 = ((const f32x4*)wp)[0];
                f32x4 w1 = ((const f32x4*)wp)[1];
                bf16x8 af;
                af[0] = (__bf16)w0[0]; af[1] = (__bf16)w0[1];
                af[2] = (__bf16)w0[2]; af[3] = (__bf16)w0[3];
                af[4] = (__bf16)w1[0]; af[5] = (__bf16)w1[1];
                af[6] = (__bf16)w1[2]; af[7] = (__bf16)w1[3];
                a[mi] = af;
            }
            #pragma unroll
            for (int ni = 0; ni < 2; ++ni) {
                const uint4* p = (const uint4*)(&comb[16*ni + llo][k0 + lhi*8]);
                b[ni] = __builtin_bit_cast(bf16x8, *p);
            }
            #pragma unroll
            for (int mi = 0; mi < 2; ++mi)
                #pragma unroll
                for (int ni = 0; ni < 2; ++ni)
                    acc[mi][ni] = __builtin_amdgcn_mfma_f32_16x16x32_bf16(a[mi], b[ni], acc[mi][ni], 0, 0, 0);
        }

        #pragma unroll
        for (int mi = 0; mi < 2; ++mi)
            #pragma unroll
            for (int ni = 0; ni < 2; ++ni)
                #pragma unroll
                for (int j = 0; j < 4; ++j) {
                    int row = m0 + 16*mi + lhi*4 + j;   // C/D: col=lane&15, row=(lane>>4)*4+reg
                    int col = n0b + 16*ni + llo;
                    out[(size_t)row * BATCH + col] = fmaxf(acc[mi][ni][j], 0.f);
                }
    } else {
        // ---- update_vector stage 1: one wave = 8 rows (2 at a time in halves) ----
        int b     = blk - 256;               // 0..1023
        int sel   = b >> 9;                  // 512 blocks pos, 512 neg
        int inner = b & 511;
        int wid   = inner * 4 + wv;          // 0..2047 per sel
        const int*   idx = sel ? neg_idx : pos_idx;
        const float* vec = sel ? neg_vec : pos_vec;

        f32x4 v4 = ((const f32x4*)vec)[hl];  // full vec per half-wave
        float pv = v4[0]*v4[0] + v4[1]*v4[1] + v4[2]*v4[2] + v4[3]*v4[3];
        #pragma unroll
        for (int off = 16; off; off >>= 1) pv += __shfl_xor(pv, off);
        float inv5nv = 1.f / (5.f * fmaxf(sqrtf(pv), EPSF));

        f32x4 a4 = {0.f, 0.f, 0.f, 0.f};
        float es = 0.f;
        int base = wid * 8;
        #pragma unroll
        for (int it = 0; it < 4; ++it) {
            int id = idx[base + 2 * it + half];
            f32x4 x = ((const f32x4*)(feats + (size_t)id * FDIM))[hl];
            float d  = x[0]*v4[0] + x[1]*v4[1] + x[2]*v4[2] + x[3]*v4[3];
            float nx = x[0]*x[0] + x[1]*x[1] + x[2]*x[2] + x[3]*x[3];
            #pragma unroll
            for (int off = 16; off; off >>= 1) {
                d  += __shfl_xor(d, off);
                nx += __shfl_xor(nx, off);
            }
            nx = fmaxf(sqrtf(nx), EPSF);
            float e = __expf(d * inv5nv / nx);   // cos/5 in [-0.2,0.2]: no max-sub
            es += e;
            a4 += e * x;
        }
        // combine halves (different rows, same feature cols)
        #pragma unroll
        for (int c = 0; c < 4; ++c) a4[c] += __shfl_xor(a4[c], 32);
        es += __shfl_xor(es, 32);

        // ---- block-level reduce: 4 waves -> 1 partial row ----
        if (lane < 32) *(f32x4*)(&red[wv][4 * hl]) = a4;
        if (lane == 0) red[wv][128] = es;
        __syncthreads();
        if (tid < 132) {
            float s = red[0][tid] + red[1][tid] + red[2][tid] + red[3][tid];
            partial[((size_t)sel * NPB + inner) * 132 + tid] = s;
        }
        __syncthreads();

        // ---- done-counter; last finisher does stage 2 inline ----
        if (tid == 0) {
            __threadfence();                       // release partial row
            unsigned old = atomicAdd(cnt, 1u);
            lastFlag = (old == 2u * NPB - 1u);
        }
        __syncthreads();
        if (lastFlag) {
            __threadfence();                       // acquire all partial rows
            int sel2 = tid >> 7, d = tid & 127;    // 256 threads = 2 sels x 128 dims
            const float* p = partial + (size_t)sel2 * NPB * 132;
            float s = 0.f, es2 = 0.f;
            for (int w = 0; w < NPB; ++w) {
                s   += p[w * 132 + d];
                es2 += p[w * 132 + 128];
            }
            out[1048576 + sel2 * 128 + d] = s / es2;
        }
    }
}

extern "C" void kernel_launch(void* const* d_in, const int* in_sizes, int n_in,
                              void* d_out, int out_size, void* d_ws, size_t ws_size,
                              hipStream_t stream) {
    const int*   nodes = (const int*)d_in[0];
    const int*   neigh = (const int*)d_in[1];
    const int*   pos_i = (const int*)d_in[2];
    const int*   neg_i = (const int*)d_in[3];
    const float* feats = (const float*)d_in[4];
    const float* W     = (const float*)d_in[5];
    const float* pvec  = (const float*)d_in[6];
    const float* nvec  = (const float*)d_in[7];
    float* out = (float*)d_out;

    float*    partial = (float*)d_ws;
    unsigned* cnt     = (unsigned*)((char*)d_ws + PARTIAL_BYTES);

    hipMemsetAsync(cnt, 0, 4, stream);   // graph-capturable memset node
    hipLaunchKernelGGL(fusedA, dim3(1280), dim3(256), 0, stream,
                       nodes, neigh, pos_i, neg_i, feats, pvec, nvec, W,
                       partial, cnt, out);
}

// Round 5
// 33.183 us; speedup vs baseline: 2.3883x; 2.3883x over previous
//
#include <hip/hip_runtime.h>
#include <hip/hip_bf16.h>
#include <stdint.h>

#define BATCH 8192
#define NSAMP 10
#define FDIM 128
#define K2 256
#define EDIM 128
#define NLAB 16384
#define EPSF 1e-6f

#define CPAD 264   // 256 + 8 bf16 pad -> 528B row stride, 16B aligned, 2-way bank alias (free)

typedef __bf16 bf16x8 __attribute__((ext_vector_type(8)));
typedef float f32x4 __attribute__((ext_vector_type(4)));

struct alignas(8) bfx4 { __hip_bfloat16 a, b, c, d; };

#define NPART 2048   // stage1 waves per sel

// ================= Kernel A =================
// blocks 0..255   : gather 32 batch rows -> LDS, then 128x32 GEMM tile + relu
// blocks 256..1279: update_vector stage 1
__global__ __launch_bounds__(256) void fusedA(
    const int* __restrict__ nodes, const int* __restrict__ neigh,
    const int* __restrict__ pos_idx, const int* __restrict__ neg_idx,
    const float* __restrict__ feats,
    const float* __restrict__ pos_vec, const float* __restrict__ neg_vec,
    const float* __restrict__ W,         // [128][256] fp32 row-major
    float* __restrict__ partial,
    float* __restrict__ out)             // [128][8192]
{
    __shared__ __hip_bfloat16 comb[32][CPAD];

    int blk  = blockIdx.x;
    int tid  = threadIdx.x;
    int lane = tid & 63;
    int wv   = tid >> 6;
    int hl   = lane & 31;        // lane within half-wave
    int half = lane >> 5;        // 0 or 1
    int hw   = wv * 2 + half;    // half-wave id 0..7

    if (blk < 256) {
        int n0 = blk * 32;       // this block's batch-row base

        // ---- phase 1: gather self + neighbor mean for 4 rows per half-wave ----
        for (int rr = 0; rr < 4; ++rr) {
            int lr  = hw * 4 + rr;           // local row 0..31
            int row = n0 + lr;
            int ids[NSAMP + 1];
            ids[0] = nodes[row];
            #pragma unroll
            for (int j = 0; j < NSAMP; ++j) ids[1 + j] = neigh[row * NSAMP + j];

            f32x4 s = ((const f32x4*)(feats + (size_t)ids[0] * FDIM))[hl];
            f32x4 acc = {0.f, 0.f, 0.f, 0.f};
            #pragma unroll
            for (int j = 0; j < NSAMP; ++j) {
                f32x4 v = ((const f32x4*)(feats + (size_t)ids[1 + j] * FDIM))[hl];
                acc += v;
            }
            acc *= 0.1f;

            bfx4 t;
            t.a = __float2bfloat16(s[0]); t.b = __float2bfloat16(s[1]);
            t.c = __float2bfloat16(s[2]); t.d = __float2bfloat16(s[3]);
            *(bfx4*)(&comb[lr][4 * hl]) = t;
            t.a = __float2bfloat16(acc[0]); t.b = __float2bfloat16(acc[1]);
            t.c = __float2bfloat16(acc[2]); t.d = __float2bfloat16(acc[3]);
            *(bfx4*)(&comb[lr][FDIM + 4 * hl]) = t;
        }
        __syncthreads();

        // ---- phase 2: out[m0..m0+31][n0..n0+31] = relu(W @ comb^T) ----
        int llo = lane & 15, lhi = lane >> 4;
        int m0 = wv * 32;

        f32x4 acc[2][2];
        #pragma unroll
        for (int i = 0; i < 2; ++i)
            #pragma unroll
            for (int j = 0; j < 2; ++j) { f32x4 z = {0.f,0.f,0.f,0.f}; acc[i][j] = z; }

        #pragma unroll
        for (int k0 = 0; k0 < K2; k0 += 32) {
            bf16x8 a[2], b[2];
            #pragma unroll
            for (int mi = 0; mi < 2; ++mi) {
                const float* wp = W + (size_t)(m0 + 16*mi + llo) * K2 + k0 + lhi*8;
                f32x4 w0 = ((const f32x4*)wp)[0];
                f32x4 w1 = ((const f32x4*)wp)[1];
                bf16x8 af;
                af[0] = (__bf16)w0[0]; af[1] = (__bf16)w0[1];
                af[2] = (__bf16)w0[2]; af[3] = (__bf16)w0[3];
                af[4] = (__bf16)w1[0]; af[5] = (__bf16)w1[1];
                af[6] = (__bf16)w1[2]; af[7] = (__bf16)w1[3];
                a[mi] = af;
            }
            #pragma unroll
            for (int ni = 0; ni < 2; ++ni) {
                const uint4* p = (const uint4*)(&comb[16*ni + llo][k0 + lhi*8]);
                b[ni] = __builtin_bit_cast(bf16x8, *p);
            }
            #pragma unroll
            for (int mi = 0; mi < 2; ++mi)
                #pragma unroll
                for (int ni = 0; ni < 2; ++ni)
                    acc[mi][ni] = __builtin_amdgcn_mfma_f32_16x16x32_bf16(a[mi], b[ni], acc[mi][ni], 0, 0, 0);
        }

        #pragma unroll
        for (int mi = 0; mi < 2; ++mi)
            #pragma unroll
            for (int ni = 0; ni < 2; ++ni)
                #pragma unroll
                for (int j = 0; j < 4; ++j) {
                    int row = m0 + 16*mi + lhi*4 + j;   // C/D: col=lane&15, row=(lane>>4)*4+reg
                    int col = n0 + 16*ni + llo;
                    out[(size_t)row * BATCH + col] = fmaxf(acc[mi][ni][j], 0.f);
                }
    } else {
        // ---- update_vector stage 1: one wave = 8 rows, 4 per half-wave,
        //      ALL 4 row-loads issued before any reduction (MLP) ----
        int b     = blk - 256;
        int sel   = b >> 9;                  // 512 blocks pos, 512 neg
        int inner = b & 511;
        int wid   = inner * 4 + wv;          // 0..2047
        const int*   idx = sel ? neg_idx : pos_idx;
        const float* vec = sel ? neg_vec : pos_vec;

        f32x4 v4 = ((const f32x4*)vec)[hl];  // full vec per half-wave
        float pv = v4[0]*v4[0] + v4[1]*v4[1] + v4[2]*v4[2] + v4[3]*v4[3];
        #pragma unroll
        for (int off = 16; off; off >>= 1) pv += __shfl_xor(pv, off);
        float inv5nv = 1.f / (5.f * fmaxf(sqrtf(pv), EPSF));

        int base = wid * 8;
        int id[4];
        #pragma unroll
        for (int it = 0; it < 4; ++it) id[it] = idx[base + 2 * it + half];

        f32x4 x[4];
        #pragma unroll
        for (int it = 0; it < 4; ++it)
            x[it] = ((const f32x4*)(feats + (size_t)id[it] * FDIM))[hl];

        float d[4], nx[4];
        #pragma unroll
        for (int it = 0; it < 4; ++it) {
            d[it]  = x[it][0]*v4[0] + x[it][1]*v4[1] + x[it][2]*v4[2] + x[it][3]*v4[3];
            nx[it] = x[it][0]*x[it][0] + x[it][1]*x[it][1] + x[it][2]*x[it][2] + x[it][3]*x[it][3];
        }
        #pragma unroll
        for (int off = 16; off; off >>= 1) {
            #pragma unroll
            for (int it = 0; it < 4; ++it) {     // 8 independent shuffles per step
                d[it]  += __shfl_xor(d[it], off);
                nx[it] += __shfl_xor(nx[it], off);
            }
        }

        f32x4 a4 = {0.f, 0.f, 0.f, 0.f};
        float es = 0.f;
        #pragma unroll
        for (int it = 0; it < 4; ++it) {
            float n2 = fmaxf(sqrtf(nx[it]), EPSF);
            float e = __expf(d[it] * inv5nv / n2);   // cos/5 in [-0.2,0.2]: no max-sub
            es += e;
            a4 += e * x[it];
        }

        // combine halves (different rows, same feature cols)
        #pragma unroll
        for (int c = 0; c < 4; ++c) a4[c] += __shfl_xor(a4[c], 32);
        es += __shfl_xor(es, 32);
        float* pw = partial + ((size_t)sel * NPART + wid) * 132;
        if (lane < 32) ((f32x4*)pw)[lane] = a4;
        if (lane == 0) pw[128] = es;
    }
}

// ================= Kernel B: stage2 (one wave per (sel,d)) =================
__global__ __launch_bounds__(256) void stage2k(
    const float* __restrict__ partial, float* __restrict__ outv)
{
    int lane = threadIdx.x & 63;
    int wv   = threadIdx.x >> 6;
    int widx = blockIdx.x * 4 + wv;   // 0..255
    int sel = widx >> 7;
    int d   = widx & 127;
    const float* p = partial + (size_t)sel * NPART * 132;
    float s = 0.f, es = 0.f;
    for (int w = lane; w < NPART; w += 64) {
        s  += p[w * 132 + d];
        es += p[w * 132 + 128];
    }
    #pragma unroll
    for (int off = 32; off; off >>= 1) {
        s  += __shfl_xor(s, off);
        es += __shfl_xor(es, off);
    }
    if (lane == 0) outv[sel * 128 + d] = s / es;
}

extern "C" void kernel_launch(void* const* d_in, const int* in_sizes, int n_in,
                              void* d_out, int out_size, void* d_ws, size_t ws_size,
                              hipStream_t stream) {
    const int*   nodes = (const int*)d_in[0];
    const int*   neigh = (const int*)d_in[1];
    const int*   pos_i = (const int*)d_in[2];
    const int*   neg_i = (const int*)d_in[3];
    const float* feats = (const float*)d_in[4];
    const float* W     = (const float*)d_in[5];
    const float* pvec  = (const float*)d_in[6];
    const float* nvec  = (const float*)d_in[7];
    float* out = (float*)d_out;

    float* partial = (float*)d_ws;   // 2*2048*132*4 = 2,162,688 B

    hipLaunchKernelGGL(fusedA, dim3(1280), dim3(256), 0, stream,
                       nodes, neigh, pos_i, neg_i, feats, pvec, nvec, W, partial, out);
    hipLaunchKernelGGL(stage2k, dim3(64), dim3(256), 0, stream,
                       partial, out + 1048576);
}

// Round 6
// 27.104 us; speedup vs baseline: 2.9240x; 1.2243x over previous
//
#include <hip/hip_runtime.h>
#include <hip/hip_bf16.h>
#include <stdint.h>

#define BATCH 8192
#define NSAMP 10
#define FDIM 128
#define K2 256
#define EDIM 128
#define NLAB 16384
#define EPSF 1e-6f

#define CPAD 264   // 256 + 8 bf16 pad -> 528B row stride, 16B aligned, 2-way bank alias (free)

typedef __bf16 bf16x8 __attribute__((ext_vector_type(8)));
typedef float f32x4 __attribute__((ext_vector_type(4)));

struct alignas(8) bfx4 { __hip_bfloat16 a, b, c, d; };

#define NPART 1024   // stage1 partial rows per sel (512 blocks x 4 waves / 2 sels)

// ================= Kernel A =================
// blocks 0..255  : gather 32 batch rows -> LDS, then 128x32 GEMM tile + relu
// blocks 256..767: update_vector stage 1 (16 rows per wave)
__global__ __launch_bounds__(256) void fusedA(
    const int* __restrict__ nodes, const int* __restrict__ neigh,
    const int* __restrict__ pos_idx, const int* __restrict__ neg_idx,
    const float* __restrict__ feats,
    const float* __restrict__ pos_vec, const float* __restrict__ neg_vec,
    const float* __restrict__ W,         // [128][256] fp32 row-major
    float* __restrict__ partial,
    float* __restrict__ out)             // [128][8192]
{
    __shared__ __hip_bfloat16 comb[32][CPAD];

    int blk  = blockIdx.x;
    int tid  = threadIdx.x;
    int lane = tid & 63;
    int wv   = tid >> 6;
    int hl   = lane & 31;        // lane within half-wave
    int half = lane >> 5;        // 0 or 1
    int hw   = wv * 2 + half;    // half-wave id 0..7

    if (blk < 256) {
        int n0 = blk * 32;       // this block's batch-row base

        // ---- phase 1: gather self + neighbor mean for 4 rows per half-wave ----
        for (int rr = 0; rr < 4; ++rr) {
            int lr  = hw * 4 + rr;           // local row 0..31
            int row = n0 + lr;
            int ids[NSAMP + 1];
            ids[0] = nodes[row];
            #pragma unroll
            for (int j = 0; j < NSAMP; ++j) ids[1 + j] = neigh[row * NSAMP + j];

            f32x4 s = ((const f32x4*)(feats + (size_t)ids[0] * FDIM))[hl];
            f32x4 acc = {0.f, 0.f, 0.f, 0.f};
            #pragma unroll
            for (int j = 0; j < NSAMP; ++j) {
                f32x4 v = ((const f32x4*)(feats + (size_t)ids[1 + j] * FDIM))[hl];
                acc += v;
            }
            acc *= 0.1f;

            bfx4 t;
            t.a = __float2bfloat16(s[0]); t.b = __float2bfloat16(s[1]);
            t.c = __float2bfloat16(s[2]); t.d = __float2bfloat16(s[3]);
            *(bfx4*)(&comb[lr][4 * hl]) = t;
            t.a = __float2bfloat16(acc[0]); t.b = __float2bfloat16(acc[1]);
            t.c = __float2bfloat16(acc[2]); t.d = __float2bfloat16(acc[3]);
            *(bfx4*)(&comb[lr][FDIM + 4 * hl]) = t;
        }
        __syncthreads();

        // ---- phase 2: out[m0..m0+31][n0..n0+31] = relu(W @ comb^T) ----
        int llo = lane & 15, lhi = lane >> 4;
        int m0 = wv * 32;

        f32x4 acc[2][2];
        #pragma unroll
        for (int i = 0; i < 2; ++i)
            #pragma unroll
            for (int j = 0; j < 2; ++j) { f32x4 z = {0.f,0.f,0.f,0.f}; acc[i][j] = z; }

        #pragma unroll
        for (int k0 = 0; k0 < K2; k0 += 32) {
            bf16x8 a[2], b[2];
            #pragma unroll
            for (int mi = 0; mi < 2; ++mi) {
                const float* wp = W + (size_t)(m0 + 16*mi + llo) * K2 + k0 + lhi*8;
                f32x4 w0 = ((const f32x4*)wp)[0];
                f32x4 w1 = ((const f32x4*)wp)[1];
                bf16x8 af;
                af[0] = (__bf16)w0[0]; af[1] = (__bf16)w0[1];
                af[2] = (__bf16)w0[2]; af[3] = (__bf16)w0[3];
                af[4] = (__bf16)w1[0]; af[5] = (__bf16)w1[1];
                af[6] = (__bf16)w1[2]; af[7] = (__bf16)w1[3];
                a[mi] = af;
            }
            #pragma unroll
            for (int ni = 0; ni < 2; ++ni) {
                const uint4* p = (const uint4*)(&comb[16*ni + llo][k0 + lhi*8]);
                b[ni] = __builtin_bit_cast(bf16x8, *p);
            }
            #pragma unroll
            for (int mi = 0; mi < 2; ++mi)
                #pragma unroll
                for (int ni = 0; ni < 2; ++ni)
                    acc[mi][ni] = __builtin_amdgcn_mfma_f32_16x16x32_bf16(a[mi], b[ni], acc[mi][ni], 0, 0, 0);
        }

        #pragma unroll
        for (int mi = 0; mi < 2; ++mi)
            #pragma unroll
            for (int ni = 0; ni < 2; ++ni)
                #pragma unroll
                for (int j = 0; j < 4; ++j) {
                    int row = m0 + 16*mi + lhi*4 + j;   // C/D: col=lane&15, row=(lane>>4)*4+reg
                    int col = n0 + 16*ni + llo;
                    out[(size_t)row * BATCH + col] = fmaxf(acc[mi][ni][j], 0.f);
                }
    } else {
        // ---- update_vector stage 1: one wave = 16 rows (two groups of 8),
        //      4 rows per half-wave per group, loads batched ----
        int b     = blk - 256;               // 0..511
        int sel   = b >> 8;                  // 256 blocks pos, 256 blocks neg
        int inner = b & 255;
        int wid   = inner * 4 + wv;          // 0..1023 per sel
        const int*   idx = sel ? neg_idx : pos_idx;
        const float* vec = sel ? neg_vec : pos_vec;

        f32x4 v4 = ((const f32x4*)vec)[hl];  // full vec per half-wave
        float pv = v4[0]*v4[0] + v4[1]*v4[1] + v4[2]*v4[2] + v4[3]*v4[3];
        #pragma unroll
        for (int off = 16; off; off >>= 1) pv += __shfl_xor(pv, off);
        float inv5nv = 1.f / (5.f * fmaxf(sqrtf(pv), EPSF));

        f32x4 a4 = {0.f, 0.f, 0.f, 0.f};
        float es = 0.f;

        #pragma unroll
        for (int g = 0; g < 2; ++g) {
            int base = wid * 16 + g * 8;
            int id[4];
            #pragma unroll
            for (int it = 0; it < 4; ++it) id[it] = idx[base + 2 * it + half];

            f32x4 x[4];
            #pragma unroll
            for (int it = 0; it < 4; ++it)
                x[it] = ((const f32x4*)(feats + (size_t)id[it] * FDIM))[hl];

            float d[4], nx[4];
            #pragma unroll
            for (int it = 0; it < 4; ++it) {
                d[it]  = x[it][0]*v4[0] + x[it][1]*v4[1] + x[it][2]*v4[2] + x[it][3]*v4[3];
                nx[it] = x[it][0]*x[it][0] + x[it][1]*x[it][1] + x[it][2]*x[it][2] + x[it][3]*x[it][3];
            }
            #pragma unroll
            for (int off = 16; off; off >>= 1) {
                #pragma unroll
                for (int it = 0; it < 4; ++it) {
                    d[it]  += __shfl_xor(d[it], off);
                    nx[it] += __shfl_xor(nx[it], off);
                }
            }
            #pragma unroll
            for (int it = 0; it < 4; ++it) {
                float n2 = fmaxf(sqrtf(nx[it]), EPSF);
                float e = __expf(d[it] * inv5nv / n2);   // cos/5 in [-0.2,0.2]: no max-sub
                es += e;
                a4 += e * x[it];
            }
        }

        // combine halves (different rows, same feature cols)
        #pragma unroll
        for (int c = 0; c < 4; ++c) a4[c] += __shfl_xor(a4[c], 32);
        es += __shfl_xor(es, 32);
        float* pw = partial + ((size_t)sel * NPART + wid) * 132;
        if (lane < 32) ((f32x4*)pw)[lane] = a4;
        if (lane == 0) pw[128] = es;
    }
}

// ================= Kernel B: stage2 (one wave per (sel,d)) =================
__global__ __launch_bounds__(256) void stage2k(
    const float* __restrict__ partial, float* __restrict__ outv)
{
    int lane = threadIdx.x & 63;
    int wv   = threadIdx.x >> 6;
    int widx = blockIdx.x * 4 + wv;   // 0..255
    int sel = widx >> 7;
    int d   = widx & 127;
    const float* p = partial + (size_t)sel * NPART * 132;
    float s = 0.f, es = 0.f;
    for (int w = lane; w < NPART; w += 64) {
        s  += p[w * 132 + d];
        es += p[w * 132 + 128];
    }
    #pragma unroll
    for (int off = 32; off; off >>= 1) {
        s  += __shfl_xor(s, off);
        es += __shfl_xor(es, off);
    }
    if (lane == 0) outv[sel * 128 + d] = s / es;
}

extern "C" void kernel_launch(void* const* d_in, const int* in_sizes, int n_in,
                              void* d_out, int out_size, void* d_ws, size_t ws_size,
                              hipStream_t stream) {
    const int*   nodes = (const int*)d_in[0];
    const int*   neigh = (const int*)d_in[1];
    const int*   pos_i = (const int*)d_in[2];
    const int*   neg_i = (const int*)d_in[3];
    const float* feats = (const float*)d_in[4];
    const float* W     = (const float*)d_in[5];
    const float* pvec  = (const float*)d_in[6];
    const float* nvec  = (const float*)d_in[7];
    float* out = (float*)d_out;

    float* partial = (float*)d_ws;   // 2*1024*132*4 = 1,081,344 B

    hipLaunchKernelGGL(fusedA, dim3(768), dim3(256), 0, stream,
                       nodes, neigh, pos_i, neg_i, feats, pvec, nvec, W, partial, out);
    hipLaunchKernelGGL(stage2k, dim3(64), dim3(256), 0, stream,
                       partial, out + 1048576);
}